// Round 7
// baseline (559.178 us; speedup 1.0000x reference)
//
#include <hip/hip_runtime.h>

#define H 128

typedef float v4f __attribute__((ext_vector_type(4)));
typedef short v8s __attribute__((ext_vector_type(8)));

// ---------------- bf16 helpers ----------------

__device__ inline unsigned short bf16_rne(float x) {
  unsigned u = __builtin_bit_cast(unsigned, x);
  unsigned r = u + 0x7FFF + ((u >> 16) & 1);
  return (unsigned short)(r >> 16);
}

__device__ inline void split_bf16(float x, unsigned short& hi, unsigned short& lo) {
  unsigned u = __builtin_bit_cast(unsigned, x);
  unsigned r = u + 0x7FFF + ((u >> 16) & 1);  // RNE round to bf16
  hi = (unsigned short)(r >> 16);
  float hf = __builtin_bit_cast(float, r & 0xFFFF0000u);
  float d = x - hf;
  unsigned ud = __builtin_bit_cast(unsigned, d);
  unsigned rd = ud + 0x7FFF + ((ud >> 16) & 1);
  lo = (unsigned short)(rd >> 16);
}

// Frag-order index for activation planes: value (row r, channel k) lives at
//   (r>>4)*2048 + (k>>5)*512 + (((k>>3)&3)*16 + (r&15))*8 + (k&7)
// so a wave's 64 lanes (q=lane>>4, m=lane&15) read one 16-row x 32-k MFMA
// A-fragment as contiguous 16B per lane: v8s index T*256 + kb*64 + lane.

// ---------------- CSR build ----------------

__global__ void hist_kernel(const int* __restrict__ dst, int* __restrict__ deg, int E) {
  int e = blockIdx.x * 256 + threadIdx.x;
  if (e < E) atomicAdd(&deg[dst[e]], 1);
}

__global__ __launch_bounds__(1024) void scan1_kernel(const int* __restrict__ deg,
                                                     int* __restrict__ incl,
                                                     int* __restrict__ blk_sum, int N) {
  __shared__ int lds[1024];
  int t = threadIdx.x;
  int i = blockIdx.x * 1024 + t;
  int v = (i < N) ? deg[i] : 0;
  lds[t] = v;
  __syncthreads();
  for (int off = 1; off < 1024; off <<= 1) {
    int x = (t >= off) ? lds[t - off] : 0;
    __syncthreads();
    lds[t] += x;
    __syncthreads();
  }
  if (i < N) incl[i] = lds[t];
  if (t == 1023) blk_sum[blockIdx.x] = lds[1023];
}

__global__ void scan2_kernel(const int* __restrict__ blk_sum, int* __restrict__ blk_off, int B) {
  __shared__ int lds[256];
  int t = threadIdx.x;
  int v = (t < B) ? blk_sum[t] : 0;
  lds[t] = v;
  __syncthreads();
  for (int off = 1; off < 256; off <<= 1) {
    int x = (t >= off) ? lds[t - off] : 0;
    __syncthreads();
    lds[t] += x;
    __syncthreads();
  }
  blk_off[t] = lds[t] - v;  // exclusive scan of block sums
}

__global__ void rowstart_kernel(const int* __restrict__ incl, const int* __restrict__ deg,
                                const int* __restrict__ blk_off, int* __restrict__ row_start,
                                int N) {
  int i = blockIdx.x * 256 + threadIdx.x;
  if (i < N) row_start[i] = blk_off[i >> 10] + incl[i] - deg[i];
}

__global__ void fill_kernel(const int* __restrict__ src, const int* __restrict__ dst,
                            const int* __restrict__ row_start, int* __restrict__ cursor,
                            int* __restrict__ csr_src, int E) {
  int e = blockIdx.x * 256 + threadIdx.x;
  if (e < E) {
    int d = dst[e];
    int p = atomicAdd(&cursor[d], 1);
    csr_src[row_start[d] + p] = src[e];
  }
}

// ---------------- feature gather: emb -> row-major hb + frag-order hi/lo planes ----------------

__global__ void gather_kernel(const float* __restrict__ emb, const int* __restrict__ node_id,
                              unsigned short* __restrict__ hb,
                              unsigned short* __restrict__ hfh,
                              unsigned short* __restrict__ hfl, int N) {
  int i = blockIdx.x * 256 + threadIdx.x;
  if (i < N * 32) {
    int n = i >> 5, g = i & 31;  // g: float4 group, channels g*4..g*4+3
    float4 v = ((const float4*)emb)[(size_t)node_id[n] * 32 + g];
    float vv[4] = {v.x, v.y, v.z, v.w};
    unsigned short hs[4], ls[4];
#pragma unroll
    for (int k = 0; k < 4; ++k) split_bf16(vv[k], hs[k], ls[k]);
    // row-major bf16 image (aggregation input)
    *(uint2*)(hb + (size_t)n * H + g * 4) =
        make_uint2((unsigned)hs[0] | ((unsigned)hs[1] << 16),
                   (unsigned)hs[2] | ((unsigned)hs[3] << 16));
    // frag-order planes (GEMM h-side input)
    size_t fi = (size_t)(n >> 4) * 2048 + (g >> 3) * 512 +
                (((g >> 1) & 3) * 16 + (n & 15)) * 8 + (g & 1) * 4;
    *(uint2*)(hfh + fi) = make_uint2((unsigned)hs[0] | ((unsigned)hs[1] << 16),
                                     (unsigned)hs[2] | ((unsigned)hs[3] << 16));
    *(uint2*)(hfl + fi) = make_uint2((unsigned)ls[0] | ((unsigned)ls[1] << 16),
                                     (unsigned)ls[2] | ((unsigned)ls[3] << 16));
  }
}

// ---------------- weight pre-split into MFMA-frag-ordered planes (r1-proven) ----------------
// Per plane (16384 shorts): e = c*2048 + kb*512 + q*128 + m*8 + j holds
// W[col=c*16+m][k=kb*32+q*8+j]. Buffer: [layer][side l/r][hi,lo][16384].

__global__ void wsplit_kernel(const float* __restrict__ W0, const float* __restrict__ W1,
                              const float* __restrict__ W2, const float* __restrict__ W3,
                              const float* __restrict__ W4, const float* __restrict__ W5,
                              unsigned short* __restrict__ Wf) {
  int idx = blockIdx.x * 256 + threadIdx.x;  // 0..98303 (6 planes x 16384)
  int sp = idx >> 14;                        // {W1l,W1r,W2l,W2r,W3l,W3r}
  int e = idx & 16383;
  const float* src = sp == 0 ? W0 : sp == 1 ? W1 : sp == 2 ? W2
                   : sp == 3 ? W3 : sp == 4 ? W4 : W5;
  int c = e >> 11;
  int kb = (e >> 9) & 3;
  int qq = (e >> 7) & 3;
  int mm = (e >> 3) & 15;
  int j = e & 7;
  int col = c * 16 + mm;
  int k = kb * 32 + qq * 8 + j;
  unsigned short hi, lo;
  split_bf16(src[col * H + k], hi, lo);
  size_t base = (size_t)(sp >> 1) * 65536 + (size_t)(sp & 1) * 32768 + e;
  Wf[base] = hi;          // hi plane
  Wf[base + 16384] = lo;  // lo plane
}

// ---------------- mean aggregation (CSR; row-major hb in, frag-order planes out) ----------------

__global__ __launch_bounds__(256) void aggregate_kernel(const unsigned short* __restrict__ hb,
                                                        const int* __restrict__ csr_src,
                                                        const int* __restrict__ row_start,
                                                        const int* __restrict__ deg,
                                                        unsigned short* __restrict__ a_hi,
                                                        unsigned short* __restrict__ a_lo, int N) {
  int node = blockIdx.x * 4 + (threadIdx.x >> 6);
  if (node >= N) return;
  int lane = threadIdx.x & 63;
  int qe = lane >> 4;  // edge slot 0..3
  int cl = lane & 15;  // channel group: channels cl*8 .. cl*8+7
  const uint4* __restrict__ h16 = (const uint4*)hb;

  int start = row_start[node];
  int d = deg[node];

  float acc[8] = {0.f, 0.f, 0.f, 0.f, 0.f, 0.f, 0.f, 0.f};

  auto accum = [&](uint4 u) {
    unsigned uu[4] = {u.x, u.y, u.z, u.w};
#pragma unroll
    for (int j = 0; j < 4; ++j) {
      acc[2 * j] += __builtin_bit_cast(float, uu[j] << 16);
      acc[2 * j + 1] += __builtin_bit_cast(float, uu[j] & 0xFFFF0000u);
    }
  };

  int e = qe;
  for (; e + 4 < d; e += 8) {
    int s0 = csr_src[start + e];
    int s1 = csr_src[start + e + 4];
    uint4 u0 = h16[(size_t)s0 * 16 + cl];
    uint4 u1 = h16[(size_t)s1 * 16 + cl];
    accum(u0);
    accum(u1);
  }
  for (; e < d; e += 4) {
    int s = csr_src[start + e];
    accum(h16[(size_t)s * 16 + cl]);
  }

#pragma unroll
  for (int j = 0; j < 8; ++j) {
    acc[j] += __shfl_xor(acc[j], 16);
    acc[j] += __shfl_xor(acc[j], 32);
  }

  float inv = 1.0f / fmaxf((float)d, 1.0f);
  if (qe < 2) {
    // lane holds channels k = cl*8 + qe*4 + j (j=0..3) -> frag-order uint2
    unsigned short hs[4], ls[4];
    int b = qe * 4;
#pragma unroll
    for (int j = 0; j < 4; ++j) split_bf16(acc[b + j] * inv, hs[j], ls[j]);
    size_t fi = (size_t)(node >> 4) * 2048 + (cl >> 2) * 512 +
                ((cl & 3) * 16 + (node & 15)) * 8 + qe * 4;
    *(uint2*)(a_hi + fi) = make_uint2((unsigned)hs[0] | ((unsigned)hs[1] << 16),
                                      (unsigned)hs[2] | ((unsigned)hs[3] << 16));
    *(uint2*)(a_lo + fi) = make_uint2((unsigned)ls[0] | ((unsigned)ls[1] << 16),
                                      (unsigned)ls[2] | ((unsigned)ls[3] << 16));
  }
}

// ---------------- frag-streaming MFMA dual-GEMM (v2: zero LDS, zero barriers) ----------------
// A (both sides, hi/lo) AND W frags loaded directly global->register from
// frag-order planes (16B/lane contiguous). W (128 KiB/layer) is shared by all
// blocks -> L2-resident; A streams from HBM. No LDS -> occupancy is
// VGPR-limited (~12-16 waves/CU vs 8 before): more loads in flight per CU is
// the point (the kernel is outstanding-bytes-bound, not BW/compute-bound).
// 256 threads, 4 waves x 2 row-tiles, waves fully independent.

template <int RELU, int FINAL>
__global__ __launch_bounds__(256) void gemm_fs(
    const unsigned short* __restrict__ agh, const unsigned short* __restrict__ agl,
    const unsigned short* hfh, const unsigned short* hfl,
    const unsigned short* __restrict__ Wfrag, const float* __restrict__ bias,
    unsigned short* hfh_out, unsigned short* hfl_out, unsigned short* hb_out,
    float* __restrict__ outf, int N) {
  int tid = threadIdx.x;
  int wave = tid >> 6, lane = tid & 63;
  int m = lane & 15, q = lane >> 4;
  int T0 = blockIdx.x * 8 + wave * 2;  // this wave's first row-tile

  const v8s* WF = (const v8s*)Wfrag;  // [side*4096 + (lo?2048:0) + c*256 + kb*64 + lane]

  v4f acc[16];  // [tr*8 + c]
#pragma unroll
  for (int t = 0; t < 16; ++t) acc[t] = (v4f){0.f, 0.f, 0.f, 0.f};

#pragma unroll
  for (int side = 0; side < 2; ++side) {
    const v8s* XH = (const v8s*)(side ? hfh : agh);
    const v8s* XL = (const v8s*)(side ? hfl : agl);
#pragma unroll
    for (int kb = 0; kb < 4; ++kb) {
      v8s ah0 = XH[(size_t)T0 * 256 + kb * 64 + lane];
      v8s ah1 = XH[(size_t)(T0 + 1) * 256 + kb * 64 + lane];
      v8s al0 = XL[(size_t)T0 * 256 + kb * 64 + lane];
      v8s al1 = XL[(size_t)(T0 + 1) * 256 + kb * 64 + lane];
#pragma unroll
      for (int c = 0; c < 8; ++c) {
        v8s bh = WF[side * 4096 + c * 256 + kb * 64 + lane];
        v8s bl = WF[side * 4096 + 2048 + c * 256 + kb * 64 + lane];
        acc[c] = __builtin_amdgcn_mfma_f32_16x16x32_bf16(ah0, bh, acc[c], 0, 0, 0);
        acc[c] = __builtin_amdgcn_mfma_f32_16x16x32_bf16(al0, bh, acc[c], 0, 0, 0);
        acc[c] = __builtin_amdgcn_mfma_f32_16x16x32_bf16(ah0, bl, acc[c], 0, 0, 0);
        acc[8 + c] = __builtin_amdgcn_mfma_f32_16x16x32_bf16(ah1, bh, acc[8 + c], 0, 0, 0);
        acc[8 + c] = __builtin_amdgcn_mfma_f32_16x16x32_bf16(al1, bh, acc[8 + c], 0, 0, 0);
        acc[8 + c] = __builtin_amdgcn_mfma_f32_16x16x32_bf16(ah1, bl, acc[8 + c], 0, 0, 0);
      }
    }
  }

  // --- epilogue: bias + activation; frag-order hi/lo + row-major hb (or fp32 final) ---
  float bv[8];
#pragma unroll
  for (int c = 0; c < 8; ++c) bv[c] = bias[c * 16 + m];
#pragma unroll
  for (int tr = 0; tr < 2; ++tr) {
    int T = T0 + tr;
#pragma unroll
    for (int c = 0; c < 8; ++c) {
      v4f a = acc[tr * 8 + c];
      size_t fb = (size_t)T * 2048 + (c >> 1) * 512 +
                  (((c & 1) * 2 + (m >> 3)) * 16) * 8 + (m & 7);
#pragma unroll
      for (int i = 0; i < 4; ++i) {
        int row = T * 16 + q * 4 + i;
        if (row < N) {
          float v = a[i] + bv[c];
          if (RELU) v = fmaxf(v, 0.f);
          if (FINAL) {
            outf[(size_t)row * H + c * 16 + m] = v;
          } else {
            unsigned short hi, lo;
            split_bf16(v, hi, lo);
            size_t fi = fb + (q * 4 + i) * 8;
            hfh_out[fi] = hi;
            hfl_out[fi] = lo;
            hb_out[(size_t)row * H + c * 16 + m] = hi;  // hb image == hi plane value
          }
        }
      }
    }
  }
}

// ---------------- launch ----------------

extern "C" void kernel_launch(void* const* d_in, const int* in_sizes, int n_in,
                              void* d_out, int out_size, void* d_ws, size_t ws_size,
                              hipStream_t stream) {
  const int* node_id = (const int*)d_in[0];
  const int* edge_index = (const int*)d_in[1];
  const float* emb = (const float*)d_in[2];
  const float* W1l = (const float*)d_in[3];
  const float* b1l = (const float*)d_in[4];
  const float* W1r = (const float*)d_in[5];
  const float* W2l = (const float*)d_in[6];
  const float* b2l = (const float*)d_in[7];
  const float* W2r = (const float*)d_in[8];
  const float* W3l = (const float*)d_in[9];
  const float* b3l = (const float*)d_in[10];
  const float* W3r = (const float*)d_in[11];

  int N = in_sizes[0];
  int E = in_sizes[1] / 2;
  const int* src = edge_index;
  const int* dst = edge_index + E;

  int ggm = (N + 127) / 128;
  size_t Np = (size_t)ggm * 128;  // plane rows padded to block multiple

  char* w = (char*)d_ws;
  auto alloc = [&](size_t bytes) {
    void* p = (void*)w;
    w += (bytes + 255) & ~(size_t)255;
    return p;
  };
  int* deg = (int*)alloc((size_t)N * 4);
  int* cursor = (int*)alloc((size_t)N * 4);
  int* row_start = (int*)alloc((size_t)N * 4);
  int* incl = (int*)alloc((size_t)N * 4);
  int* blk_sum = (int*)alloc(1024);
  int* blk_off = (int*)alloc(1024);
  int* csr_src = (int*)alloc((size_t)E * 4);
  unsigned short* hb = (unsigned short*)alloc((size_t)N * H * 2);   // row-major bf16 image
  unsigned short* hfh = (unsigned short*)alloc(Np * H * 2);         // frag-order h hi
  unsigned short* hfl = (unsigned short*)alloc(Np * H * 2);         // frag-order h lo
  unsigned short* agh = (unsigned short*)alloc(Np * H * 2);         // frag-order aggr hi
  unsigned short* agl = (unsigned short*)alloc(Np * H * 2);         // frag-order aggr lo
  unsigned short* Wf = (unsigned short*)alloc((size_t)3 * 65536 * 2);

  hipMemsetAsync(deg, 0, (size_t)N * 4, stream);
  hipMemsetAsync(cursor, 0, (size_t)N * 4, stream);

  hist_kernel<<<(E + 255) / 256, 256, 0, stream>>>(dst, deg, E);
  int SB = (N + 1023) / 1024;
  scan1_kernel<<<SB, 1024, 0, stream>>>(deg, incl, blk_sum, N);
  scan2_kernel<<<1, 256, 0, stream>>>(blk_sum, blk_off, SB);
  rowstart_kernel<<<(N + 255) / 256, 256, 0, stream>>>(incl, deg, blk_off, row_start, N);
  fill_kernel<<<(E + 255) / 256, 256, 0, stream>>>(src, dst, row_start, cursor, csr_src, E);

  gather_kernel<<<(N * 32 + 255) / 256, 256, 0, stream>>>(emb, node_id, hb, hfh, hfl, N);
  // planes order: [W1l, W1r, W2l, W2r, W3l, W3r]
  wsplit_kernel<<<384, 256, 0, stream>>>(W1l, W1r, W2l, W2r, W3l, W3r, Wf);

  int gag = (N + 3) / 4;

  // layer 1
  aggregate_kernel<<<gag, 256, 0, stream>>>(hb, csr_src, row_start, deg, agh, agl, N);
  gemm_fs<1, 0><<<ggm, 256, 0, stream>>>(agh, agl, hfh, hfl, Wf + 0 * 65536, b1l,
                                         hfh, hfl, hb, nullptr, N);

  // layer 2
  aggregate_kernel<<<gag, 256, 0, stream>>>(hb, csr_src, row_start, deg, agh, agl, N);
  gemm_fs<1, 0><<<ggm, 256, 0, stream>>>(agh, agl, hfh, hfl, Wf + 1 * 65536, b2l,
                                         hfh, hfl, hb, nullptr, N);

  // layer 3 -> fp32 d_out
  aggregate_kernel<<<gag, 256, 0, stream>>>(hb, csr_src, row_start, deg, agh, agl, N);
  gemm_fs<0, 1><<<ggm, 256, 0, stream>>>(agh, agl, hfh, hfl, Wf + 2 * 65536, b3l,
                                         nullptr, nullptr, nullptr, (float*)d_out, N);
}

// Round 8
// 465.904 us; speedup vs baseline: 1.2002x; 1.2002x over previous
//
#include <hip/hip_runtime.h>

#define H 128

typedef float v4f __attribute__((ext_vector_type(4)));
typedef short v8s __attribute__((ext_vector_type(8)));

// ---------------- bf16 helpers ----------------

__device__ inline unsigned short bf16_rne(float x) {
  unsigned u = __builtin_bit_cast(unsigned, x);
  unsigned r = u + 0x7FFF + ((u >> 16) & 1);
  return (unsigned short)(r >> 16);
}

__device__ inline void split_bf16(float x, unsigned short& hi, unsigned short& lo) {
  unsigned u = __builtin_bit_cast(unsigned, x);
  unsigned r = u + 0x7FFF + ((u >> 16) & 1);  // RNE round to bf16
  hi = (unsigned short)(r >> 16);
  float hf = __builtin_bit_cast(float, r & 0xFFFF0000u);
  float d = x - hf;
  unsigned ud = __builtin_bit_cast(unsigned, d);
  unsigned rd = ud + 0x7FFF + ((ud >> 16) & 1);
  lo = (unsigned short)(rd >> 16);
}

// Frag-order index for bf16 planes: value (row r, channel k) lives at
//   (r>>4)*2048 + (k>>5)*512 + (((k>>3)&3)*16 + (r&15))*8 + (k&7)
// A wave (q=lane>>4, m=lane&15) reads one 16x32 A-frag as v8s idx
// T*256 + kb*64 + lane (lane m <-> row T*16+m, q <-> channels kb*32+q*8..+7).

// ---------------- CSR build ----------------

__global__ void hist_kernel(const int* __restrict__ dst, int* __restrict__ deg, int E) {
  int e = blockIdx.x * 256 + threadIdx.x;
  if (e < E) atomicAdd(&deg[dst[e]], 1);
}

__global__ __launch_bounds__(1024) void scan1_kernel(const int* __restrict__ deg,
                                                     int* __restrict__ incl,
                                                     int* __restrict__ blk_sum, int N) {
  __shared__ int lds[1024];
  int t = threadIdx.x;
  int i = blockIdx.x * 1024 + t;
  int v = (i < N) ? deg[i] : 0;
  lds[t] = v;
  __syncthreads();
  for (int off = 1; off < 1024; off <<= 1) {
    int x = (t >= off) ? lds[t - off] : 0;
    __syncthreads();
    lds[t] += x;
    __syncthreads();
  }
  if (i < N) incl[i] = lds[t];
  if (t == 1023) blk_sum[blockIdx.x] = lds[1023];
}

// rowstart with scan2 fused: every block redundantly scans the (<=128)
// per-block sums in LDS, then computes row_start. Kills one dispatch.
__global__ void rowstart_kernel(const int* __restrict__ incl, const int* __restrict__ deg,
                                const int* __restrict__ blk_sum, int* __restrict__ row_start,
                                int N, int SB) {
  __shared__ int excl[128];
  int t = threadIdx.x;
  int v = 0;
  if (t < 128) {
    v = (t < SB) ? blk_sum[t] : 0;
    excl[t] = v;
  }
  __syncthreads();
  for (int off = 1; off < 128; off <<= 1) {
    int x = (t >= off && t < 128) ? excl[t - off] : 0;
    __syncthreads();
    if (t < 128) excl[t] += x;
    __syncthreads();
  }
  if (t < 128) excl[t] -= v;  // exclusive scan
  __syncthreads();
  int i = blockIdx.x * 256 + t;
  if (i < N) row_start[i] = excl[i >> 10] + incl[i] - deg[i];
}

__global__ void fill_kernel(const int* __restrict__ src, const int* __restrict__ dst,
                            const int* __restrict__ row_start, int* __restrict__ cursor,
                            int* __restrict__ csr_src, int E) {
  int e = blockIdx.x * 256 + threadIdx.x;
  if (e < E) {
    int d = dst[e];
    int p = atomicAdd(&cursor[d], 1);
    csr_src[row_start[d] + p] = src[e];
  }
}

// ---------------- fused gather + weight pre-split ----------------
// Blocks [0, GB): emb gather -> row-major hb (hi) + frag-order hfl (lo).
// Blocks [GB, GB+384): 6x [128x128] W -> frag-order hi/lo planes
//   per plane (16384 shorts): e = c*2048 + kb*512 + q*128 + m*8 + j holds
//   W[col=c*16+m][k=kb*32+q*8+j]; buffer [layer][side][hi,lo][16384].

__global__ void gatherw_kernel(const float* __restrict__ emb, const int* __restrict__ node_id,
                               unsigned short* __restrict__ hb, unsigned short* __restrict__ hfl,
                               const float* __restrict__ W0, const float* __restrict__ W1,
                               const float* __restrict__ W2, const float* __restrict__ W3,
                               const float* __restrict__ W4, const float* __restrict__ W5,
                               unsigned short* __restrict__ Wf, int N, int GB) {
  if ((int)blockIdx.x < GB) {
    int i = blockIdx.x * 256 + threadIdx.x;
    if (i < N * 32) {
      int n = i >> 5, g = i & 31;  // g: float4 group, channels g*4..g*4+3
      float4 v = ((const float4*)emb)[(size_t)node_id[n] * 32 + g];
      float vv[4] = {v.x, v.y, v.z, v.w};
      unsigned short hs[4], ls[4];
#pragma unroll
      for (int k = 0; k < 4; ++k) split_bf16(vv[k], hs[k], ls[k]);
      *(uint2*)(hb + (size_t)n * H + g * 4) =
          make_uint2((unsigned)hs[0] | ((unsigned)hs[1] << 16),
                     (unsigned)hs[2] | ((unsigned)hs[3] << 16));
      size_t fi = (size_t)(n >> 4) * 2048 + (g >> 3) * 512 +
                  (((g >> 1) & 3) * 16 + (n & 15)) * 8 + (g & 1) * 4;
      *(uint2*)(hfl + fi) = make_uint2((unsigned)ls[0] | ((unsigned)ls[1] << 16),
                                       (unsigned)ls[2] | ((unsigned)ls[3] << 16));
    }
  } else {
    int idx = ((int)blockIdx.x - GB) * 256 + threadIdx.x;  // 0..98303
    int sp = idx >> 14;
    int e = idx & 16383;
    const float* src = sp == 0 ? W0 : sp == 1 ? W1 : sp == 2 ? W2
                     : sp == 3 ? W3 : sp == 4 ? W4 : W5;
    int c = e >> 11;
    int kb = (e >> 9) & 3;
    int qq = (e >> 7) & 3;
    int mm = (e >> 3) & 15;
    int j = e & 7;
    unsigned short hi, lo;
    split_bf16(src[(c * 16 + mm) * H + kb * 32 + qq * 8 + j], hi, lo);
    size_t base = (size_t)(sp >> 1) * 65536 + (size_t)(sp & 1) * 32768 + e;
    Wf[base] = hi;
    Wf[base + 16384] = lo;
  }
}

// ---------------- mean aggregation (CSR; row-major hb in, frag-order ag planes out) ----------------

__global__ __launch_bounds__(256) void aggregate_kernel(const unsigned short* __restrict__ hb,
                                                        const int* __restrict__ csr_src,
                                                        const int* __restrict__ row_start,
                                                        const int* __restrict__ deg,
                                                        unsigned short* __restrict__ a_hi,
                                                        unsigned short* __restrict__ a_lo, int N) {
  int node = blockIdx.x * 4 + (threadIdx.x >> 6);
  if (node >= N) return;
  int lane = threadIdx.x & 63;
  int qe = lane >> 4;  // edge slot 0..3
  int cl = lane & 15;  // channel group: channels cl*8 .. cl*8+7
  const uint4* __restrict__ h16 = (const uint4*)hb;

  int start = row_start[node];
  int d = deg[node];

  float acc[8] = {0.f, 0.f, 0.f, 0.f, 0.f, 0.f, 0.f, 0.f};

  auto accum = [&](uint4 u) {
    unsigned uu[4] = {u.x, u.y, u.z, u.w};
#pragma unroll
    for (int j = 0; j < 4; ++j) {
      acc[2 * j] += __builtin_bit_cast(float, uu[j] << 16);
      acc[2 * j + 1] += __builtin_bit_cast(float, uu[j] & 0xFFFF0000u);
    }
  };

  int e = qe;
  for (; e + 4 < d; e += 8) {
    int s0 = csr_src[start + e];
    int s1 = csr_src[start + e + 4];
    uint4 u0 = h16[(size_t)s0 * 16 + cl];
    uint4 u1 = h16[(size_t)s1 * 16 + cl];
    accum(u0);
    accum(u1);
  }
  for (; e < d; e += 4) {
    int s = csr_src[start + e];
    accum(h16[(size_t)s * 16 + cl]);
  }

#pragma unroll
  for (int j = 0; j < 8; ++j) {
    acc[j] += __shfl_xor(acc[j], 16);
    acc[j] += __shfl_xor(acc[j], 32);
  }

  float inv = 1.0f / fmaxf((float)d, 1.0f);
  if (qe < 2) {
    // lane holds channels k = cl*8 + qe*4 + j (j=0..3) -> frag-order uint2
    unsigned short hs[4], ls[4];
    int b = qe * 4;
#pragma unroll
    for (int j = 0; j < 4; ++j) split_bf16(acc[b + j] * inv, hs[j], ls[j]);
    size_t fi = (size_t)(node >> 4) * 2048 + (cl >> 2) * 512 +
                ((cl & 3) * 16 + (node & 15)) * 8 + qe * 4;
    *(uint2*)(a_hi + fi) = make_uint2((unsigned)hs[0] | ((unsigned)hs[1] << 16),
                                      (unsigned)hs[2] | ((unsigned)hs[3] << 16));
    *(uint2*)(a_lo + fi) = make_uint2((unsigned)ls[0] | ((unsigned)ls[1] << 16),
                                      (unsigned)ls[2] | ((unsigned)ls[3] << 16));
  }
}

// ---------------- frag-streaming MFMA dual-GEMM (r6 engine; h-hi from row-major hb) ----------------
// A loads global->register: ag hi/lo + h lo from frag planes (16B/lane
// contiguous); h hi read from row-major hb (lane (q,m): 16B at
// (T*16+m)*128 + kb*32 + q*8 — same values, no hfh plane needed). W staged
// per-side into 64 KiB static LDS (stride-1 b128, conflict-free; r6-proven).
// Epilogue writes row-major hb + frag hfl (or fp32 final). In-place hb
// update is row-local (proven aliasing class).

template <int RELU, int FINAL>
__global__ __launch_bounds__(256) void gemm_fs(
    const unsigned short* __restrict__ agh, const unsigned short* __restrict__ agl,
    const unsigned short* hb, const unsigned short* hfl,
    const unsigned short* __restrict__ Wfrag, const float* __restrict__ bias,
    unsigned short* hb_out, unsigned short* hfl_out, float* __restrict__ outf, int N) {
  __shared__ __align__(16) unsigned short Wsh[32768];  // 64 KiB: [hi 16384][lo 16384]

  int tid = threadIdx.x;
  int wave = tid >> 6, lane = tid & 63;
  int m = lane & 15, q = lane >> 4;
  int T0 = blockIdx.x * 8 + wave * 2;  // this wave's first row-tile

  v4f acc[16];  // [tr*8 + c]
#pragma unroll
  for (int t = 0; t < 16; ++t) acc[t] = (v4f){0.f, 0.f, 0.f, 0.f};

  for (int side = 0; side < 2; ++side) {
    const v8s* Wg = (const v8s*)(Wfrag + side * 32768);

    __syncthreads();  // previous side's W reads complete before overwrite
#pragma unroll
    for (int i = 0; i < 16; ++i) ((v8s*)Wsh)[tid + i * 256] = Wg[tid + i * 256];
    __syncthreads();

    const v8s* WF = (const v8s*)Wsh;
#pragma unroll
    for (int kb = 0; kb < 4; ++kb) {
      v8s ah0, ah1, al0, al1;
      if (side == 0) {  // aggr side: frag-order planes
        const v8s* XH = (const v8s*)agh;
        const v8s* XL = (const v8s*)agl;
        ah0 = XH[(size_t)T0 * 256 + kb * 64 + lane];
        ah1 = XH[(size_t)(T0 + 1) * 256 + kb * 64 + lane];
        al0 = XL[(size_t)T0 * 256 + kb * 64 + lane];
        al1 = XL[(size_t)(T0 + 1) * 256 + kb * 64 + lane];
      } else {  // h side: hi from row-major hb, lo from frag plane
        ah0 = *(const v8s*)(hb + ((size_t)T0 * 16 + m) * H + kb * 32 + q * 8);
        ah1 = *(const v8s*)(hb + ((size_t)(T0 + 1) * 16 + m) * H + kb * 32 + q * 8);
        const v8s* XL = (const v8s*)hfl;
        al0 = XL[(size_t)T0 * 256 + kb * 64 + lane];
        al1 = XL[(size_t)(T0 + 1) * 256 + kb * 64 + lane];
      }
#pragma unroll
      for (int c = 0; c < 8; ++c) {
        v8s bh = WF[c * 256 + kb * 64 + lane];
        v8s bl = WF[2048 + c * 256 + kb * 64 + lane];
        acc[c] = __builtin_amdgcn_mfma_f32_16x16x32_bf16(ah0, bh, acc[c], 0, 0, 0);
        acc[c] = __builtin_amdgcn_mfma_f32_16x16x32_bf16(al0, bh, acc[c], 0, 0, 0);
        acc[c] = __builtin_amdgcn_mfma_f32_16x16x32_bf16(ah0, bl, acc[c], 0, 0, 0);
        acc[8 + c] = __builtin_amdgcn_mfma_f32_16x16x32_bf16(ah1, bh, acc[8 + c], 0, 0, 0);
        acc[8 + c] = __builtin_amdgcn_mfma_f32_16x16x32_bf16(al1, bh, acc[8 + c], 0, 0, 0);
        acc[8 + c] = __builtin_amdgcn_mfma_f32_16x16x32_bf16(ah1, bl, acc[8 + c], 0, 0, 0);
      }
    }
  }

  // --- epilogue: bias + activation; row-major hb + frag hfl (or fp32 final) ---
  float bv[8];
#pragma unroll
  for (int c = 0; c < 8; ++c) bv[c] = bias[c * 16 + m];
#pragma unroll
  for (int tr = 0; tr < 2; ++tr) {
    int T = T0 + tr;
#pragma unroll
    for (int c = 0; c < 8; ++c) {
      v4f a = acc[tr * 8 + c];
      size_t fb = (size_t)T * 2048 + (c >> 1) * 512 +
                  (((c & 1) * 2 + (m >> 3)) * 16) * 8 + (m & 7);
#pragma unroll
      for (int i = 0; i < 4; ++i) {
        int row = T * 16 + q * 4 + i;
        if (row < N) {
          float v = a[i] + bv[c];
          if (RELU) v = fmaxf(v, 0.f);
          if (FINAL) {
            outf[(size_t)row * H + c * 16 + m] = v;
          } else {
            unsigned short hi, lo;
            split_bf16(v, hi, lo);
            hb_out[(size_t)row * H + c * 16 + m] = hi;
            hfl_out[fb + (q * 4 + i) * 8] = lo;
          }
        }
      }
    }
  }
}

// ---------------- launch ----------------

extern "C" void kernel_launch(void* const* d_in, const int* in_sizes, int n_in,
                              void* d_out, int out_size, void* d_ws, size_t ws_size,
                              hipStream_t stream) {
  const int* node_id = (const int*)d_in[0];
  const int* edge_index = (const int*)d_in[1];
  const float* emb = (const float*)d_in[2];
  const float* W1l = (const float*)d_in[3];
  const float* b1l = (const float*)d_in[4];
  const float* W1r = (const float*)d_in[5];
  const float* W2l = (const float*)d_in[6];
  const float* b2l = (const float*)d_in[7];
  const float* W2r = (const float*)d_in[8];
  const float* W3l = (const float*)d_in[9];
  const float* b3l = (const float*)d_in[10];
  const float* W3r = (const float*)d_in[11];

  int N = in_sizes[0];
  int E = in_sizes[1] / 2;
  const int* src = edge_index;
  const int* dst = edge_index + E;

  int ggm = (N + 127) / 128;
  size_t Np = (size_t)ggm * 128;  // rows padded to block multiple

  char* w = (char*)d_ws;
  auto alloc = [&](size_t bytes) {
    void* p = (void*)w;
    w += (bytes + 255) & ~(size_t)255;
    return p;
  };
  int* deg = (int*)alloc((size_t)2 * N * 4);  // deg + cursor contiguous: ONE memset
  int* cursor = deg + N;
  int* row_start = (int*)alloc((size_t)N * 4);
  int* incl = (int*)alloc((size_t)N * 4);
  int* blk_sum = (int*)alloc(1024);
  int* csr_src = (int*)alloc((size_t)E * 4);
  unsigned short* hb = (unsigned short*)alloc(Np * H * 2);   // row-major h hi (bf16)
  unsigned short* hfl = (unsigned short*)alloc(Np * H * 2);  // frag-order h lo
  unsigned short* agh = (unsigned short*)alloc(Np * H * 2);  // frag-order aggr hi
  unsigned short* agl = (unsigned short*)alloc(Np * H * 2);  // frag-order aggr lo
  unsigned short* Wf = (unsigned short*)alloc((size_t)3 * 65536 * 2);

  hipMemsetAsync(deg, 0, (size_t)2 * N * 4, stream);

  hist_kernel<<<(E + 255) / 256, 256, 0, stream>>>(dst, deg, E);
  int SB = (N + 1023) / 1024;
  scan1_kernel<<<SB, 1024, 0, stream>>>(deg, incl, blk_sum, N);
  rowstart_kernel<<<(N + 255) / 256, 256, 0, stream>>>(incl, deg, blk_sum, row_start, N, SB);
  fill_kernel<<<(E + 255) / 256, 256, 0, stream>>>(src, dst, row_start, cursor, csr_src, E);

  int GB = (N * 32 + 255) / 256;
  gatherw_kernel<<<GB + 384, 256, 0, stream>>>(emb, node_id, hb, hfl,
                                               W1l, W1r, W2l, W2r, W3l, W3r, Wf, N, GB);

  int gag = (N + 3) / 4;

  // layer 1
  aggregate_kernel<<<gag, 256, 0, stream>>>(hb, csr_src, row_start, deg, agh, agl, N);
  gemm_fs<1, 0><<<ggm, 256, 0, stream>>>(agh, agl, hb, hfl, Wf + 0 * 65536, b1l,
                                         hb, hfl, nullptr, N);

  // layer 2
  aggregate_kernel<<<gag, 256, 0, stream>>>(hb, csr_src, row_start, deg, agh, agl, N);
  gemm_fs<1, 0><<<ggm, 256, 0, stream>>>(agh, agl, hb, hfl, Wf + 1 * 65536, b2l,
                                         hb, hfl, nullptr, N);

  // layer 3 -> fp32 d_out
  aggregate_kernel<<<gag, 256, 0, stream>>>(hb, csr_src, row_start, deg, agh, agl, N);
  gemm_fs<0, 1><<<ggm, 256, 0, stream>>>(agh, agl, hb, hfl, Wf + 2 * 65536, b3l,
                                         nullptr, nullptr, (float*)d_out, N);
}